// Round 5
// baseline (378.081 us; speedup 1.0000x reference)
//
#include <hip/hip_runtime.h>
#include <hip/hip_fp16.h>

#define N_NODES 100000
#define N_EDGES 1600000
#define IN_DIM  128
#define OUT_DIM 64
#define HEADS   4
#define SLOPE   0.2f
#define CLIP_LO 0.005f
#define CLIP_HI 10.0f
#define STASH   128

typedef short bf16x8 __attribute__((ext_vector_type(8)));
typedef float f32x4  __attribute__((ext_vector_type(4)));

__device__ __forceinline__ short f2bf(float x) {
    union { float f; unsigned u; } v; v.f = x;
    unsigned r = (v.u + 0x7FFF + ((v.u >> 16) & 1)) >> 16;   // RNE
    return (short)r;
}
__device__ __forceinline__ unsigned short f2hbits(float x) {
    union { __half h; unsigned short u; } c; c.h = __float2half(x); return c.u;
}

// ---------------------------------------------------------------------------
// prep: WcatT[n][i] = bf16(W[k][i][j]) with n=k*64+j  (B matrix, [256][128])
// ---------------------------------------------------------------------------
__global__ __launch_bounds__(256) void prep_kernel(const float* __restrict__ W,
                                                   short* __restrict__ WcatT) {
    int idx = blockIdx.x * 256 + threadIdx.x;
    if (idx >= 256 * 128) return;
    int n = idx >> 7, i = idx & 127;
    int k = n >> 6, j = n & 63;
    WcatT[idx] = f2bf(W[((size_t)k * IN_DIM + i) * OUT_DIM + j]);
}

// ---------------------------------------------------------------------------
// gemm_mfma: hw[n][k*64+j] (fp16) = h @ Wcat via bf16 MFMA.
// Fused epilogue: sArrS[n][k] = hw[n][k*64:]·a1[k], sArrD[n][k] = ·a2[k]
// (from f32 accumulators, 16-lane shfl reduce). C staged via LDS union w/ As.
// ---------------------------------------------------------------------------
__global__ __launch_bounds__(256) void gemm_mfma(const float* __restrict__ h,
                                                 const short* __restrict__ WcatT,
                                                 const float* __restrict__ a,
                                                 __half* __restrict__ hw,
                                                 float* __restrict__ sS,
                                                 float* __restrict__ sD) {
    __shared__ __align__(16) char smem[64 * 264 * 2];          // 33.8KB union
    short (*As)[136]          = (short(*)[136])smem;           // 17.4KB footprint
    unsigned short (*Cs)[264] = (unsigned short(*)[264])smem;
    const int row0 = blockIdx.x * 64;
    const int tid  = threadIdx.x;

    // stage 64 rows of h as bf16
#pragma unroll
    for (int u = 0; u < 4; ++u) {
        int e = (tid + u * 256) * 8;
        int r = e >> 7, c = e & 127;
        int grow = row0 + r; if (grow >= N_NODES) grow = N_NODES - 1;
        const float* hp = h + (size_t)grow * IN_DIM + c;
        float4 v0 = *(const float4*)hp;
        float4 v1 = *(const float4*)(hp + 4);
        bf16x8 b;
        b[0]=f2bf(v0.x); b[1]=f2bf(v0.y); b[2]=f2bf(v0.z); b[3]=f2bf(v0.w);
        b[4]=f2bf(v1.x); b[5]=f2bf(v1.y); b[6]=f2bf(v1.z); b[7]=f2bf(v1.w);
        *(bf16x8*)&As[r][c] = b;
    }
    __syncthreads();

    const int wv = tid >> 6, lane = tid & 63;
    const int lrow = lane & 15;
    const int lk   = (lane >> 4) * 8;

    bf16x8 bfr[4][4];
#pragma unroll
    for (int nt = 0; nt < 4; ++nt)
#pragma unroll
        for (int ks = 0; ks < 4; ++ks)
            bfr[nt][ks] = *(const bf16x8*)(WcatT + (size_t)(wv * 64 + nt * 16 + lrow) * 128 + ks * 32 + lk);

    f32x4 acc[4][4] = {};
#pragma unroll
    for (int ks = 0; ks < 4; ++ks) {
        bf16x8 afr[4];
#pragma unroll
        for (int mt = 0; mt < 4; ++mt)
            afr[mt] = *(const bf16x8*)&As[mt * 16 + lrow][ks * 32 + lk];
#pragma unroll
        for (int mt = 0; mt < 4; ++mt)
#pragma unroll
            for (int nt = 0; nt < 4; ++nt)
                acc[mt][nt] = __builtin_amdgcn_mfma_f32_16x16x32_bf16(afr[mt], bfr[nt][ks], acc[mt][nt], 0, 0, 0);
    }

    // ---- fused score epilogue (regs + shfl only) ----
    // wave wv owns head k=wv; lane's col j = nt*16+lrow
    float a1v[4], a2v[4];
#pragma unroll
    for (int nt = 0; nt < 4; ++nt) {
        a1v[nt] = a[wv * 128 + nt * 16 + lrow];
        a2v[nt] = a[wv * 128 + 64 + nt * 16 + lrow];
    }
    const int rgrp = lane >> 4;
#pragma unroll
    for (int mt = 0; mt < 4; ++mt)
#pragma unroll
        for (int reg = 0; reg < 4; ++reg) {
            float p1 = acc[mt][0][reg]*a1v[0] + acc[mt][1][reg]*a1v[1]
                     + acc[mt][2][reg]*a1v[2] + acc[mt][3][reg]*a1v[3];
            float p2 = acc[mt][0][reg]*a2v[0] + acc[mt][1][reg]*a2v[1]
                     + acc[mt][2][reg]*a2v[2] + acc[mt][3][reg]*a2v[3];
#pragma unroll
            for (int off = 1; off < 16; off <<= 1) {
                p1 += __shfl_xor(p1, off);
                p2 += __shfl_xor(p2, off);
            }
            if ((lane & 15) == 0) {
                int g = row0 + mt * 16 + rgrp * 4 + reg;
                if (g < N_NODES) {
                    sS[(size_t)g * 4 + wv] = p1;
                    sD[(size_t)g * 4 + wv] = p2;
                }
            }
        }

    __syncthreads();   // all As reads done before Cs overwrite (LDS union)

    // stage C into LDS (C/D layout: col=lane&15, row=(lane>>4)*4+reg)
#pragma unroll
    for (int mt = 0; mt < 4; ++mt)
#pragma unroll
        for (int reg = 0; reg < 4; ++reg) {
            int r = mt * 16 + rgrp * 4 + reg;
#pragma unroll
            for (int nt = 0; nt < 4; ++nt)
                Cs[r][wv * 64 + nt * 16 + lrow] = f2hbits(acc[mt][nt][reg]);
        }
    __syncthreads();

    // coalesced writeout: thread t -> row t>>2, 128B segment
    {
        const int r  = tid >> 2;
        const int c0 = (tid & 3) * 64;
        int g = row0 + r;
        if (g < N_NODES) {
            const uint4* src = (const uint4*)&Cs[r][c0];
            uint4* dst = (uint4*)(hw + (size_t)g * 256 + c0);
#pragma unroll
            for (int u = 0; u < 8; ++u) dst[u] = src[u];
        }
    }
}

// ---------------------------------------------------------------------------
__device__ __forceinline__ float edge_e(float x) {
    x = x > 0.f ? x : SLOPE * x;
    float ev = __expf(x);
    return fminf(fmaxf(ev, CLIP_LO), CLIP_HI);
}

__global__ __launch_bounds__(256) void deg_hist(const int* __restrict__ edges,
                                                int* __restrict__ deg) {
    int e = blockIdx.x * 256 + threadIdx.x;
    if (e >= N_EDGES) return;
    atomicAdd(&deg[edges[N_EDGES + e]], 1);
}

__global__ __launch_bounds__(256) void deg_blocksum(const int* __restrict__ deg,
                                                    int* __restrict__ partial) {
    __shared__ int red[256];
    int base = blockIdx.x * 1024 + threadIdx.x * 4;
    int s = 0;
#pragma unroll
    for (int u = 0; u < 4; ++u) { int i = base + u; if (i < N_NODES) s += deg[i]; }
    red[threadIdx.x] = s; __syncthreads();
    for (int off = 128; off > 0; off >>= 1) {
        if (threadIdx.x < off) red[threadIdx.x] += red[threadIdx.x + off];
        __syncthreads();
    }
    if (threadIdx.x == 0) partial[blockIdx.x] = red[0];
}

__global__ __launch_bounds__(128) void scan_partials(int* __restrict__ partial, int nb) {
    __shared__ int sm[128];
    int t = threadIdx.x;
    sm[t] = (t < nb) ? partial[t] : 0;
    __syncthreads();
    if (t == 0) {
        int run = 0;
        for (int i = 0; i < nb; ++i) { int v = sm[i]; sm[i] = run; run += v; }
    }
    __syncthreads();
    if (t < nb) partial[t] = sm[t];
}

__global__ __launch_bounds__(256) void deg_scan_write(const int* __restrict__ deg,
                                                      const int* __restrict__ partial,
                                                      int* __restrict__ row_off,
                                                      int* __restrict__ cursor) {
    __shared__ int sc[2][256];
    int t = threadIdx.x;
    int base = blockIdx.x * 1024 + t * 4;
    int v[4]; int s = 0;
#pragma unroll
    for (int u = 0; u < 4; ++u) { int i = base + u; v[u] = (i < N_NODES) ? deg[i] : 0; s += v[u]; }
    sc[0][t] = s; __syncthreads();
    int cur = 0;
    for (int off = 1; off < 256; off <<= 1) {
        int x = sc[cur][t];
        if (t >= off) x += sc[cur][t - off];
        sc[cur ^ 1][t] = x; __syncthreads(); cur ^= 1;
    }
    int excl = sc[cur][t] - s;
    int run = partial[blockIdx.x] + excl;
#pragma unroll
    for (int u = 0; u < 4; ++u) {
        int i = base + u;
        if (i < N_NODES) { row_off[i] = run; cursor[i] = run; run += v[u]; }
    }
}

// scatter: src-only CSR — one 4B random write per edge
__global__ __launch_bounds__(256) void scatter_kernel(const int* __restrict__ edges,
                                                      int* __restrict__ cursor,
                                                      int* __restrict__ csr_src) {
    int e = blockIdx.x * 256 + threadIdx.x;
    if (e >= N_EDGES) return;
    int s = edges[e], d = edges[N_EDGES + e];
    int pos = atomicAdd(&cursor[d], 1);
    csr_src[pos] = s;
}

// ---------------------------------------------------------------------------
__device__ __forceinline__ void fmacc(float4& acg, uint2 g, float w) {
    __half2 h0 = *(__half2*)&g.x, h1 = *(__half2*)&g.y;
    float2 f0 = __half22float2(h0), f1 = __half22float2(h1);
    acg.x += w * f0.x; acg.y += w * f0.y; acg.z += w * f1.x; acg.w += w * f1.y;
}

// msg_csr: one wave per dst. Pass1: gather sArrS[src] (L2-resident), compute
// clipped-exp weights, stash float4 in LDS, reduce denom. Pass2: LDS weight +
// 8B hw gather, unrolled x4. Zero atomics, one coalesced store.
__global__ __launch_bounds__(256) void msg_csr(const int* __restrict__ row_off,
                                               const int* __restrict__ deg,
                                               const int* __restrict__ csr_src,
                                               const float4* __restrict__ sArrS,
                                               const float4* __restrict__ sArrD,
                                               const __half* __restrict__ hw,
                                               float* __restrict__ out) {
    __shared__ float4 stash[4][STASH];       // 8KB
    const int wslot = threadIdx.x >> 6;
    int wid  = (blockIdx.x * 256 + threadIdx.x) >> 6;
    int lane = threadIdx.x & 63;
    if (wid >= N_NODES) return;
    const int start = row_off[wid];
    const int dg    = deg[wid];
    const float4 dv = sArrD[wid];

    // pass 1: weights + denominators
    float4 den = make_float4(0.f, 0.f, 0.f, 0.f);
    for (int i = lane; i < dg; i += 64) {
        int s = csr_src[start + i];
        float4 sv = sArrS[s];
        float4 w;
        w.x = edge_e(sv.x + dv.x);
        w.y = edge_e(sv.y + dv.y);
        w.z = edge_e(sv.z + dv.z);
        w.w = edge_e(sv.w + dv.w);
        den.x += w.x; den.y += w.y; den.z += w.z; den.w += w.w;
        if (i < STASH) stash[wslot][i] = w;
    }
#pragma unroll
    for (int off = 32; off > 0; off >>= 1) {
        den.x += __shfl_xor(den.x, off);
        den.y += __shfl_xor(den.y, off);
        den.z += __shfl_xor(den.z, off);
        den.w += __shfl_xor(den.w, off);
    }
    const int kh = lane >> 4;
    float invk = kh == 0 ? den.x : kh == 1 ? den.y : kh == 2 ? den.z : den.w;
    invk = invk > 0.f ? 0.25f / invk : 0.f;
    __builtin_amdgcn_wave_barrier();   // stash visible within wave (same wave wrote it)

    // pass 2
    const size_t loff = (size_t)(lane << 2);
    const float* wst = (const float*)&stash[wslot][0];
    float4 acg = make_float4(0.f, 0.f, 0.f, 0.f);
    if (dg <= STASH) {
        int i = 0;
        for (; i + 4 <= dg; i += 4) {
            int s0 = csr_src[start + i];
            int s1 = csr_src[start + i + 1];
            int s2 = csr_src[start + i + 2];
            int s3 = csr_src[start + i + 3];
            uint2 g0 = *(const uint2*)(hw + (((size_t)s0) << 8) + loff);
            uint2 g1 = *(const uint2*)(hw + (((size_t)s1) << 8) + loff);
            uint2 g2 = *(const uint2*)(hw + (((size_t)s2) << 8) + loff);
            uint2 g3 = *(const uint2*)(hw + (((size_t)s3) << 8) + loff);
            float w0 = wst[(i + 0) * 4 + kh] * invk;
            float w1 = wst[(i + 1) * 4 + kh] * invk;
            float w2 = wst[(i + 2) * 4 + kh] * invk;
            float w3 = wst[(i + 3) * 4 + kh] * invk;
            fmacc(acg, g0, w0);
            fmacc(acg, g1, w1);
            fmacc(acg, g2, w2);
            fmacc(acg, g3, w3);
        }
        for (; i < dg; ++i) {
            int s = csr_src[start + i];
            uint2 g = *(const uint2*)(hw + (((size_t)s) << 8) + loff);
            fmacc(acg, g, wst[i * 4 + kh] * invk);
        }
    } else {
        // rare fallback (deg > STASH): recompute weights
        float dk = kh == 0 ? dv.x : kh == 1 ? dv.y : kh == 2 ? dv.z : dv.w;
        for (int i = 0; i < dg; ++i) {
            int s = csr_src[start + i];
            const float* svp = (const float*)(sArrS + s);
            float w = edge_e(svp[kh] + dk) * invk;
            uint2 g = *(const uint2*)(hw + (((size_t)s) << 8) + loff);
            fmacc(acg, g, w);
        }
    }

#pragma unroll
    for (int off = 16; off < 64; off <<= 1) {
        acg.x += __shfl_xor(acg.x, off);
        acg.y += __shfl_xor(acg.y, off);
        acg.z += __shfl_xor(acg.z, off);
        acg.w += __shfl_xor(acg.w, off);
    }
    if (lane < 16) *(float4*)(out + (size_t)wid * OUT_DIM + (lane << 2)) =
        make_float4(acg.x, acg.y, acg.z, acg.w);
}

// ---------------------------------------------------------------------------
extern "C" void kernel_launch(void* const* d_in, const int* in_sizes, int n_in,
                              void* d_out, int out_size, void* d_ws, size_t ws_size,
                              hipStream_t stream) {
    const float* h     = (const float*)d_in[0];
    const int*   edges = (const int*)d_in[1];
    const float* W     = (const float*)d_in[2];
    const float* a     = (const float*)d_in[3];
    float* out = (float*)d_out;

    char* ws = (char*)d_ws;
    __half* hw      = (__half*)(ws);                    // 51,200,000 B  [N][256] f16
    float*  sArrS   = (float*) (ws + 51200000);         //  1,600,000 B  [N][4]
    float*  sArrD   = (float*) (ws + 52800000);         //  1,600,000 B  [N][4]
    short*  WcatT   = (short*) (ws + 54400000);         //     65,536 B
    int*    deg     = (int*)   (ws + 54465536);         //    400,000 B
    int*    row_off = (int*)   (ws + 54865536);         //    400,000 B
    int*    cursor  = (int*)   (ws + 55265536);         //    400,000 B
    int*    partial = (int*)   (ws + 55665536);         //      4,096 B
    int*    csr_src = (int*)   (ws + 55669632);         //  6,400,000 B  (~62.1 MB)

    const int NB_SCAN = (N_NODES + 1023) / 1024;        // 98

    hipMemsetAsync(deg, 0, (size_t)N_NODES * sizeof(int), stream);

    prep_kernel<<<128, 256, 0, stream>>>(W, WcatT);
    gemm_mfma<<<(N_NODES + 63) / 64, 256, 0, stream>>>(h, WcatT, a, hw, sArrS, sArrD);

    deg_hist<<<(N_EDGES + 255) / 256, 256, 0, stream>>>(edges, deg);
    deg_blocksum<<<NB_SCAN, 256, 0, stream>>>(deg, partial);
    scan_partials<<<1, 128, 0, stream>>>(partial, NB_SCAN);
    deg_scan_write<<<NB_SCAN, 256, 0, stream>>>(deg, partial, row_off, cursor);
    scatter_kernel<<<(N_EDGES + 255) / 256, 256, 0, stream>>>(edges, cursor, csr_src);

    msg_csr<<<(N_NODES + 3) / 4, 256, 0, stream>>>(row_off, deg, csr_src,
                                                   (const float4*)sArrS,
                                                   (const float4*)sArrD, hw, out);
}

// Round 6
// 325.752 us; speedup vs baseline: 1.1606x; 1.1606x over previous
//
#include <hip/hip_runtime.h>
#include <hip/hip_fp16.h>

#define N_NODES 100000
#define N_EDGES 1600000
#define IN_DIM  128
#define OUT_DIM 64
#define HEADS   4
#define SLOPE   0.2f
#define CLIP_LO 0.005f
#define CLIP_HI 10.0f

typedef short bf16x8 __attribute__((ext_vector_type(8)));
typedef float f32x4  __attribute__((ext_vector_type(4)));

__device__ __forceinline__ short f2bf(float x) {
    union { float f; unsigned u; } v; v.f = x;
    unsigned r = (v.u + 0x7FFF + ((v.u >> 16) & 1)) >> 16;   // RNE
    return (short)r;
}
__device__ __forceinline__ unsigned short f2hbits(float x) {
    union { __half h; unsigned short u; } c; c.h = __float2half(x); return c.u;
}
__device__ __forceinline__ float hbits2f(unsigned short b) {
    union { __half h; unsigned short u; } c; c.u = b; return __half2float(c.h);
}

// ---------------------------------------------------------------------------
// prep: WcatT[n][i] = bf16(W[k][i][j]) with n=k*64+j; Wa for score GEMV
// ---------------------------------------------------------------------------
__global__ __launch_bounds__(256) void prep_kernel(const float* __restrict__ W,
                                                   const float* __restrict__ a,
                                                   short* __restrict__ WcatT,
                                                   float* __restrict__ Wa) {
    int idx = blockIdx.x * 256 + threadIdx.x;
    if (idx < 256 * 128) {
        int n = idx >> 7, i = idx & 127;
        int k = n >> 6, j = n & 63;
        WcatT[idx] = f2bf(W[((size_t)k * IN_DIM + i) * OUT_DIM + j]);
    } else if (idx < 256 * 128 + 1024) {
        int o = idx - 256 * 128;
        int k = o >> 8, half = (o >> 7) & 1, i = o & 127;
        const float* wrow = W + ((size_t)k * IN_DIM + i) * OUT_DIM;
        const float* av   = a + k * 2 * OUT_DIM + half * OUT_DIM;
        float acc = 0.f;
#pragma unroll 8
        for (int j = 0; j < OUT_DIM; ++j) acc += wrow[j] * av[j];
        Wa[o] = acc;
    }
}

// ---------------------------------------------------------------------------
// s_kernel: exact f32 scores via h @ Wa
// ---------------------------------------------------------------------------
__global__ __launch_bounds__(256) void s_kernel(const float* __restrict__ h,
                                                const float* __restrict__ Wa,
                                                float* __restrict__ sArr) {
    __shared__ __align__(16) float wa_s[HEADS * 2 * IN_DIM];
    for (int t = threadIdx.x; t < HEADS * 2 * IN_DIM; t += 256) wa_s[t] = Wa[t];
    __syncthreads();
    int n = blockIdx.x * 256 + threadIdx.x;
    if (n >= N_NODES) return;
    const float4* hv = (const float4*)(h + (size_t)n * IN_DIM);
    const float4* wv = (const float4*)wa_s;
    float acc[8] = {0.f,0.f,0.f,0.f,0.f,0.f,0.f,0.f};
    for (int i4 = 0; i4 < IN_DIM / 4; ++i4) {
        float4 hx = hv[i4];
#pragma unroll
        for (int k2 = 0; k2 < 8; ++k2) {
            float4 w = wv[k2 * (IN_DIM / 4) + i4];
            acc[k2] += hx.x * w.x + hx.y * w.y + hx.z * w.z + hx.w * w.w;
        }
    }
    float* o = sArr + (size_t)n * 8;
#pragma unroll
    for (int k = 0; k < 4; ++k) { o[k] = acc[2 * k]; o[4 + k] = acc[2 * k + 1]; }
}

// ---------------------------------------------------------------------------
// gemm_mfma: hw[n][k*64+j] (fp16, node-major [N][256]) = h @ Wcat via bf16 MFMA
// Epilogue staged through LDS for coalesced dwordx4 stores. (R4-proven)
// ---------------------------------------------------------------------------
__global__ __launch_bounds__(256) void gemm_mfma(const float* __restrict__ h,
                                                 const short* __restrict__ WcatT,
                                                 __half* __restrict__ hw) {
    __shared__ __align__(16) short As[64][136];            // 17.4KB
    __shared__ __align__(16) unsigned short Cs[64][264];   // 33.8KB
    const int row0 = blockIdx.x * 64;
    const int tid  = threadIdx.x;

#pragma unroll
    for (int u = 0; u < 4; ++u) {
        int e = (tid + u * 256) * 8;
        int r = e >> 7, c = e & 127;
        int grow = row0 + r; if (grow >= N_NODES) grow = N_NODES - 1;
        const float* hp = h + (size_t)grow * IN_DIM + c;
        float4 v0 = *(const float4*)hp;
        float4 v1 = *(const float4*)(hp + 4);
        bf16x8 b;
        b[0]=f2bf(v0.x); b[1]=f2bf(v0.y); b[2]=f2bf(v0.z); b[3]=f2bf(v0.w);
        b[4]=f2bf(v1.x); b[5]=f2bf(v1.y); b[6]=f2bf(v1.z); b[7]=f2bf(v1.w);
        *(bf16x8*)&As[r][c] = b;
    }
    __syncthreads();

    const int wv = tid >> 6, lane = tid & 63;
    const int lrow = lane & 15;
    const int lk   = (lane >> 4) * 8;

    bf16x8 bfr[4][4];
#pragma unroll
    for (int nt = 0; nt < 4; ++nt)
#pragma unroll
        for (int ks = 0; ks < 4; ++ks)
            bfr[nt][ks] = *(const bf16x8*)(WcatT + (size_t)(wv * 64 + nt * 16 + lrow) * 128 + ks * 32 + lk);

    f32x4 acc[4][4] = {};
#pragma unroll
    for (int ks = 0; ks < 4; ++ks) {
        bf16x8 afr[4];
#pragma unroll
        for (int mt = 0; mt < 4; ++mt)
            afr[mt] = *(const bf16x8*)&As[mt * 16 + lrow][ks * 32 + lk];
#pragma unroll
        for (int mt = 0; mt < 4; ++mt)
#pragma unroll
            for (int nt = 0; nt < 4; ++nt)
                acc[mt][nt] = __builtin_amdgcn_mfma_f32_16x16x32_bf16(afr[mt], bfr[nt][ks], acc[mt][nt], 0, 0, 0);
    }

    const int rgrp = lane >> 4;
#pragma unroll
    for (int mt = 0; mt < 4; ++mt)
#pragma unroll
        for (int reg = 0; reg < 4; ++reg) {
            int r = mt * 16 + rgrp * 4 + reg;
#pragma unroll
            for (int nt = 0; nt < 4; ++nt)
                Cs[r][wv * 64 + nt * 16 + lrow] = f2hbits(acc[mt][nt][reg]);
        }
    __syncthreads();

    {
        const int r  = tid >> 2;
        const int c0 = (tid & 3) * 64;
        int g = row0 + r;
        if (g < N_NODES) {
            const uint4* src = (const uint4*)&Cs[r][c0];
            uint4* dst = (uint4*)(hw + (size_t)g * 256 + c0);
#pragma unroll
            for (int u = 0; u < 8; ++u) dst[u] = src[u];
        }
    }
}

// ---------------------------------------------------------------------------
__device__ __forceinline__ float edge_e(float x) {
    x = x > 0.f ? x : SLOPE * x;
    float ev = __expf(x);
    return fminf(fmaxf(ev, CLIP_LO), CLIP_HI);
}

__global__ __launch_bounds__(256) void deg_hist(const int* __restrict__ edges,
                                                int* __restrict__ deg) {
    int e = blockIdx.x * 256 + threadIdx.x;
    if (e >= N_EDGES) return;
    atomicAdd(&deg[edges[N_EDGES + e]], 1);
}

__global__ __launch_bounds__(256) void deg_blocksum(const int* __restrict__ deg,
                                                    int* __restrict__ partial) {
    __shared__ int red[256];
    int base = blockIdx.x * 1024 + threadIdx.x * 4;
    int s = 0;
#pragma unroll
    for (int u = 0; u < 4; ++u) { int i = base + u; if (i < N_NODES) s += deg[i]; }
    red[threadIdx.x] = s; __syncthreads();
    for (int off = 128; off > 0; off >>= 1) {
        if (threadIdx.x < off) red[threadIdx.x] += red[threadIdx.x + off];
        __syncthreads();
    }
    if (threadIdx.x == 0) partial[blockIdx.x] = red[0];
}

__global__ __launch_bounds__(128) void scan_partials(int* __restrict__ partial, int nb) {
    __shared__ int sm[128];
    int t = threadIdx.x;
    sm[t] = (t < nb) ? partial[t] : 0;
    __syncthreads();
    if (t == 0) {
        int run = 0;
        for (int i = 0; i < nb; ++i) { int v = sm[i]; sm[i] = run; run += v; }
    }
    __syncthreads();
    if (t < nb) partial[t] = sm[t];
}

__global__ __launch_bounds__(256) void deg_scan_write(const int* __restrict__ deg,
                                                      const int* __restrict__ partial,
                                                      int* __restrict__ row_off,
                                                      int* __restrict__ cursor) {
    __shared__ int sc[2][256];
    int t = threadIdx.x;
    int base = blockIdx.x * 1024 + t * 4;
    int v[4]; int s = 0;
#pragma unroll
    for (int u = 0; u < 4; ++u) { int i = base + u; v[u] = (i < N_NODES) ? deg[i] : 0; s += v[u]; }
    sc[0][t] = s; __syncthreads();
    int cur = 0;
    for (int off = 1; off < 256; off <<= 1) {
        int x = sc[cur][t];
        if (t >= off) x += sc[cur][t - off];
        sc[cur ^ 1][t] = x; __syncthreads(); cur ^= 1;
    }
    int excl = sc[cur][t] - s;
    int run = partial[blockIdx.x] + excl;
#pragma unroll
    for (int u = 0; u < 4; ++u) {
        int i = base + u;
        if (i < N_NODES) { row_off[i] = run; cursor[i] = run; run += v[u]; }
    }
}

__global__ __launch_bounds__(256) void scatter_kernel(const int* __restrict__ edges,
                                                      const float* __restrict__ sArr,
                                                      int* __restrict__ cursor,
                                                      uint4* __restrict__ csr) {
    int e = blockIdx.x * 256 + threadIdx.x;
    if (e >= N_EDGES) return;
    int s = edges[e], d = edges[N_EDGES + e];
    float4 ss = *(const float4*)(sArr + (size_t)s * 8);
    float4 sd = *(const float4*)(sArr + (size_t)d * 8 + 4);
    unsigned w0 = f2hbits(edge_e(ss.x + sd.x));
    unsigned w1 = f2hbits(edge_e(ss.y + sd.y));
    unsigned w2 = f2hbits(edge_e(ss.z + sd.z));
    unsigned w3 = f2hbits(edge_e(ss.w + sd.w));
    uint4 rec;
    rec.x = (unsigned)s;
    rec.y = w0 | (w1 << 16);
    rec.z = w2 | (w3 << 16);
    rec.w = 0;
    int pos = atomicAdd(&cursor[d], 1);
    csr[pos] = rec;
}

// ---------------------------------------------------------------------------
__device__ __forceinline__ float pickw(const uint4& r, int kh) {
    unsigned wp = (kh & 2) ? r.z : r.y;
    return hbits2f((unsigned short)((kh & 1) ? (wp >> 16) : (wp & 0xffff)));
}
__device__ __forceinline__ void fmacc8(float4& lo, float4& hi, uint4 g, float w) {
    __half2 h0 = *(__half2*)&g.x, h1 = *(__half2*)&g.y;
    __half2 h2 = *(__half2*)&g.z, h3 = *(__half2*)&g.w;
    float2 f0 = __half22float2(h0), f1 = __half22float2(h1);
    float2 f2 = __half22float2(h2), f3 = __half22float2(h3);
    lo.x += w * f0.x; lo.y += w * f0.y; lo.z += w * f1.x; lo.w += w * f1.y;
    hi.x += w * f2.x; hi.y += w * f2.y; hi.z += w * f3.x; hi.w += w * f3.y;
}

// msg_csr: one wave per dst. Lane decomposition: es=lane>>5 (edge slot),
// kh=(lane&31)>>3 (head), cg=lane&7 (col octet). 16B gather/lane, 2 edges per
// slot, unrolled x4 => 8 edges in flight, 1 VMEM/edge.
__global__ __launch_bounds__(256) void msg_csr(const int* __restrict__ row_off,
                                               const int* __restrict__ deg,
                                               const uint4* __restrict__ csr,
                                               const __half* __restrict__ hw,
                                               float* __restrict__ out) {
    int wid  = (blockIdx.x * 256 + threadIdx.x) >> 6;
    int lane = threadIdx.x & 63;
    if (wid >= N_NODES) return;
    const int start = row_off[wid];
    const int dg    = deg[wid];

    // pass 1: denominators (all lanes, strided)
    float4 den = make_float4(0.f, 0.f, 0.f, 0.f);
    for (int i = lane; i < dg; i += 64) {
        uint4 rec = csr[start + i];
        den.x += hbits2f((unsigned short)(rec.y & 0xffff));
        den.y += hbits2f((unsigned short)(rec.y >> 16));
        den.z += hbits2f((unsigned short)(rec.z & 0xffff));
        den.w += hbits2f((unsigned short)(rec.z >> 16));
    }
#pragma unroll
    for (int off = 32; off > 0; off >>= 1) {
        den.x += __shfl_xor(den.x, off);
        den.y += __shfl_xor(den.y, off);
        den.z += __shfl_xor(den.z, off);
        den.w += __shfl_xor(den.w, off);
    }
    const int es = lane >> 5;           // edge slot 0/1
    const int kh = (lane & 31) >> 3;    // head
    const int cg = lane & 7;            // col octet
    float invk = kh == 0 ? den.x : kh == 1 ? den.y : kh == 2 ? den.z : den.w;
    invk = invk > 0.f ? 0.25f / invk : 0.f;

    // pass 2: 16B/lane gathers, 2 edges/slot, unroll x4 (8 edges in flight)
    const size_t coff = (size_t)((kh << 6) + (cg << 3));   // halfs within row
    float4 alo = make_float4(0.f,0.f,0.f,0.f), ahi = make_float4(0.f,0.f,0.f,0.f);
    int i = 0;
    for (; i + 8 <= dg; i += 8) {
        uint4 r0 = csr[start + i     + es];
        uint4 r1 = csr[start + i + 2 + es];
        uint4 r2 = csr[start + i + 4 + es];
        uint4 r3 = csr[start + i + 6 + es];
        uint4 g0 = *(const uint4*)(hw + (((size_t)r0.x) << 8) + coff);
        uint4 g1 = *(const uint4*)(hw + (((size_t)r1.x) << 8) + coff);
        uint4 g2 = *(const uint4*)(hw + (((size_t)r2.x) << 8) + coff);
        uint4 g3 = *(const uint4*)(hw + (((size_t)r3.x) << 8) + coff);
        float w0 = pickw(r0, kh) * invk;
        float w1 = pickw(r1, kh) * invk;
        float w2 = pickw(r2, kh) * invk;
        float w3 = pickw(r3, kh) * invk;
        fmacc8(alo, ahi, g0, w0);
        fmacc8(alo, ahi, g1, w1);
        fmacc8(alo, ahi, g2, w2);
        fmacc8(alo, ahi, g3, w3);
    }
    for (; i < dg; i += 2) {
        int idx = i + es; 
        bool valid = idx < dg;
        if (idx >= dg) idx = dg - 1;
        uint4 r = csr[start + idx];
        uint4 g = *(const uint4*)(hw + (((size_t)r.x) << 8) + coff);
        float w = valid ? pickw(r, kh) * invk : 0.f;
        fmacc8(alo, ahi, g, w);
    }

    // reduce: heads (xor 8, 16) then edge slots (xor 32)
#pragma unroll
    for (int off = 8; off < 64; off <<= 1) {
        if (off == 32 || off >= 8) {
            alo.x += __shfl_xor(alo.x, off); alo.y += __shfl_xor(alo.y, off);
            alo.z += __shfl_xor(alo.z, off); alo.w += __shfl_xor(alo.w, off);
            ahi.x += __shfl_xor(ahi.x, off); ahi.y += __shfl_xor(ahi.y, off);
            ahi.z += __shfl_xor(ahi.z, off); ahi.w += __shfl_xor(ahi.w, off);
        }
    }
    if (lane < 8) {
        float* op = out + (size_t)wid * OUT_DIM + (cg << 3);
        *(float4*)op       = alo;
        *(float4*)(op + 4) = ahi;
    }
}

// ---------------------------------------------------------------------------
extern "C" void kernel_launch(void* const* d_in, const int* in_sizes, int n_in,
                              void* d_out, int out_size, void* d_ws, size_t ws_size,
                              hipStream_t stream) {
    const float* h     = (const float*)d_in[0];
    const int*   edges = (const int*)d_in[1];
    const float* W     = (const float*)d_in[2];
    const float* a     = (const float*)d_in[3];
    float* out = (float*)d_out;

    char* ws = (char*)d_ws;
    __half* hw      = (__half*)(ws);                    // 51,200,000 B  [N][256] f16
    float*  sArr    = (float*) (ws + 51200000);         //  3,200,000 B
    float*  Wa      = (float*) (ws + 54400000);         //      4,096 B
    short*  WcatT   = (short*) (ws + 54404096);         //     65,536 B
    int*    deg     = (int*)   (ws + 54469632);         //    400,000 B
    int*    row_off = (int*)   (ws + 54869632);         //    400,000 B
    int*    cursor  = (int*)   (ws + 55269632);         //    400,000 B
    int*    partial = (int*)   (ws + 55669632);         //      4,096 B
    uint4*  csr     = (uint4*) (ws + 55673728);         // 25,600,000 B

    const int NB_SCAN = (N_NODES + 1023) / 1024;        // 98

    hipMemsetAsync(deg, 0, (size_t)N_NODES * sizeof(int), stream);

    prep_kernel<<<132, 256, 0, stream>>>(W, a, WcatT, Wa);
    s_kernel<<<(N_NODES + 255) / 256, 256, 0, stream>>>(h, Wa, sArr);
    gemm_mfma<<<(N_NODES + 63) / 64, 256, 0, stream>>>(h, WcatT, hw);

    deg_hist<<<(N_EDGES + 255) / 256, 256, 0, stream>>>(edges, deg);
    deg_blocksum<<<NB_SCAN, 256, 0, stream>>>(deg, partial);
    scan_partials<<<1, 128, 0, stream>>>(partial, NB_SCAN);
    deg_scan_write<<<NB_SCAN, 256, 0, stream>>>(deg, partial, row_off, cursor);
    scatter_kernel<<<(N_EDGES + 255) / 256, 256, 0, stream>>>(edges, sArr, cursor, csr);

    msg_csr<<<(N_NODES + 3) / 4, 256, 0, stream>>>(row_off, deg, csr, hw, out);
}

// Round 7
// 323.515 us; speedup vs baseline: 1.1687x; 1.0069x over previous
//
#include <hip/hip_runtime.h>
#include <hip/hip_fp16.h>

#define N_NODES 100000
#define N_EDGES 1600000
#define IN_DIM  128
#define OUT_DIM 64
#define HEADS   4
#define SLOPE   0.2f
#define CLIP_LO 0.005f
#define CLIP_HI 10.0f

typedef short bf16x8 __attribute__((ext_vector_type(8)));
typedef float f32x4  __attribute__((ext_vector_type(4)));

__device__ __forceinline__ short f2bf(float x) {
    union { float f; unsigned u; } v; v.f = x;
    unsigned r = (v.u + 0x7FFF + ((v.u >> 16) & 1)) >> 16;   // RNE
    return (short)r;
}
__device__ __forceinline__ unsigned short f2hbits(float x) {
    union { __half h; unsigned short u; } c; c.h = __float2half(x); return c.u;
}
__device__ __forceinline__ float hbits2f(unsigned short b) {
    union { __half h; unsigned short u; } c; c.u = b; return __half2float(c.h);
}

// ---------------------------------------------------------------------------
// prep: WcatT[n][i] = bf16(W[k][i][j]) with n=k*64+j; Wa for score GEMV
// ---------------------------------------------------------------------------
__global__ __launch_bounds__(256) void prep_kernel(const float* __restrict__ W,
                                                   const float* __restrict__ a,
                                                   short* __restrict__ WcatT,
                                                   float* __restrict__ Wa) {
    int idx = blockIdx.x * 256 + threadIdx.x;
    if (idx < 256 * 128) {
        int n = idx >> 7, i = idx & 127;
        int k = n >> 6, j = n & 63;
        WcatT[idx] = f2bf(W[((size_t)k * IN_DIM + i) * OUT_DIM + j]);
    } else if (idx < 256 * 128 + 1024) {
        int o = idx - 256 * 128;
        int k = o >> 8, half = (o >> 7) & 1, i = o & 127;
        const float* wrow = W + ((size_t)k * IN_DIM + i) * OUT_DIM;
        const float* av   = a + k * 2 * OUT_DIM + half * OUT_DIM;
        float acc = 0.f;
#pragma unroll 8
        for (int j = 0; j < OUT_DIM; ++j) acc += wrow[j] * av[j];
        Wa[o] = acc;
    }
}

// ---------------------------------------------------------------------------
// s_kernel: exact f32 scores via h @ Wa
// ---------------------------------------------------------------------------
__global__ __launch_bounds__(256) void s_kernel(const float* __restrict__ h,
                                                const float* __restrict__ Wa,
                                                float* __restrict__ sArr) {
    __shared__ __align__(16) float wa_s[HEADS * 2 * IN_DIM];
    for (int t = threadIdx.x; t < HEADS * 2 * IN_DIM; t += 256) wa_s[t] = Wa[t];
    __syncthreads();
    int n = blockIdx.x * 256 + threadIdx.x;
    if (n >= N_NODES) return;
    const float4* hv = (const float4*)(h + (size_t)n * IN_DIM);
    const float4* wv = (const float4*)wa_s;
    float acc[8] = {0.f,0.f,0.f,0.f,0.f,0.f,0.f,0.f};
    for (int i4 = 0; i4 < IN_DIM / 4; ++i4) {
        float4 hx = hv[i4];
#pragma unroll
        for (int k2 = 0; k2 < 8; ++k2) {
            float4 w = wv[k2 * (IN_DIM / 4) + i4];
            acc[k2] += hx.x * w.x + hx.y * w.y + hx.z * w.z + hx.w * w.w;
        }
    }
    float* o = sArr + (size_t)n * 8;
#pragma unroll
    for (int k = 0; k < 4; ++k) { o[k] = acc[2 * k]; o[4 + k] = acc[2 * k + 1]; }
}

// ---------------------------------------------------------------------------
// gemm_mfma: hw[n][k*64+j] (fp16, node-major [N][256]) = h @ Wcat via bf16 MFMA
// Epilogue staged through LDS for coalesced dwordx4 stores. (R4-proven)
// ---------------------------------------------------------------------------
__global__ __launch_bounds__(256) void gemm_mfma(const float* __restrict__ h,
                                                 const short* __restrict__ WcatT,
                                                 __half* __restrict__ hw) {
    __shared__ __align__(16) short As[64][136];            // 17.4KB
    __shared__ __align__(16) unsigned short Cs[64][264];   // 33.8KB
    const int row0 = blockIdx.x * 64;
    const int tid  = threadIdx.x;

#pragma unroll
    for (int u = 0; u < 4; ++u) {
        int e = (tid + u * 256) * 8;
        int r = e >> 7, c = e & 127;
        int grow = row0 + r; if (grow >= N_NODES) grow = N_NODES - 1;
        const float* hp = h + (size_t)grow * IN_DIM + c;
        float4 v0 = *(const float4*)hp;
        float4 v1 = *(const float4*)(hp + 4);
        bf16x8 b;
        b[0]=f2bf(v0.x); b[1]=f2bf(v0.y); b[2]=f2bf(v0.z); b[3]=f2bf(v0.w);
        b[4]=f2bf(v1.x); b[5]=f2bf(v1.y); b[6]=f2bf(v1.z); b[7]=f2bf(v1.w);
        *(bf16x8*)&As[r][c] = b;
    }
    __syncthreads();

    const int wv = tid >> 6, lane = tid & 63;
    const int lrow = lane & 15;
    const int lk   = (lane >> 4) * 8;

    bf16x8 bfr[4][4];
#pragma unroll
    for (int nt = 0; nt < 4; ++nt)
#pragma unroll
        for (int ks = 0; ks < 4; ++ks)
            bfr[nt][ks] = *(const bf16x8*)(WcatT + (size_t)(wv * 64 + nt * 16 + lrow) * 128 + ks * 32 + lk);

    f32x4 acc[4][4] = {};
#pragma unroll
    for (int ks = 0; ks < 4; ++ks) {
        bf16x8 afr[4];
#pragma unroll
        for (int mt = 0; mt < 4; ++mt)
            afr[mt] = *(const bf16x8*)&As[mt * 16 + lrow][ks * 32 + lk];
#pragma unroll
        for (int mt = 0; mt < 4; ++mt)
#pragma unroll
            for (int nt = 0; nt < 4; ++nt)
                acc[mt][nt] = __builtin_amdgcn_mfma_f32_16x16x32_bf16(afr[mt], bfr[nt][ks], acc[mt][nt], 0, 0, 0);
    }

    const int rgrp = lane >> 4;
#pragma unroll
    for (int mt = 0; mt < 4; ++mt)
#pragma unroll
        for (int reg = 0; reg < 4; ++reg) {
            int r = mt * 16 + rgrp * 4 + reg;
#pragma unroll
            for (int nt = 0; nt < 4; ++nt)
                Cs[r][wv * 64 + nt * 16 + lrow] = f2hbits(acc[mt][nt][reg]);
        }
    __syncthreads();

    {
        const int r  = tid >> 2;
        const int c0 = (tid & 3) * 64;
        int g = row0 + r;
        if (g < N_NODES) {
            const uint4* src = (const uint4*)&Cs[r][c0];
            uint4* dst = (uint4*)(hw + (size_t)g * 256 + c0);
#pragma unroll
            for (int u = 0; u < 8; ++u) dst[u] = src[u];
        }
    }
}

// ---------------------------------------------------------------------------
__device__ __forceinline__ float edge_e(float x) {
    x = x > 0.f ? x : SLOPE * x;
    float ev = __expf(x);
    return fminf(fmaxf(ev, CLIP_LO), CLIP_HI);
}

__global__ __launch_bounds__(256) void deg_hist(const int* __restrict__ edges,
                                                int* __restrict__ deg) {
    int e = blockIdx.x * 256 + threadIdx.x;
    if (e >= N_EDGES) return;
    atomicAdd(&deg[edges[N_EDGES + e]], 1);
}

__global__ __launch_bounds__(256) void deg_blocksum(const int* __restrict__ deg,
                                                    int* __restrict__ partial) {
    __shared__ int red[256];
    int base = blockIdx.x * 1024 + threadIdx.x * 4;
    int s = 0;
#pragma unroll
    for (int u = 0; u < 4; ++u) { int i = base + u; if (i < N_NODES) s += deg[i]; }
    red[threadIdx.x] = s; __syncthreads();
    for (int off = 128; off > 0; off >>= 1) {
        if (threadIdx.x < off) red[threadIdx.x] += red[threadIdx.x + off];
        __syncthreads();
    }
    if (threadIdx.x == 0) partial[blockIdx.x] = red[0];
}

__global__ __launch_bounds__(128) void scan_partials(int* __restrict__ partial, int nb) {
    __shared__ int sm[128];
    int t = threadIdx.x;
    sm[t] = (t < nb) ? partial[t] : 0;
    __syncthreads();
    if (t == 0) {
        int run = 0;
        for (int i = 0; i < nb; ++i) { int v = sm[i]; sm[i] = run; run += v; }
    }
    __syncthreads();
    if (t < nb) partial[t] = sm[t];
}

__global__ __launch_bounds__(256) void deg_scan_write(const int* __restrict__ deg,
                                                      const int* __restrict__ partial,
                                                      int* __restrict__ row_off,
                                                      int* __restrict__ cursor) {
    __shared__ int sc[2][256];
    int t = threadIdx.x;
    int base = blockIdx.x * 1024 + t * 4;
    int v[4]; int s = 0;
#pragma unroll
    for (int u = 0; u < 4; ++u) { int i = base + u; v[u] = (i < N_NODES) ? deg[i] : 0; s += v[u]; }
    sc[0][t] = s; __syncthreads();
    int cur = 0;
    for (int off = 1; off < 256; off <<= 1) {
        int x = sc[cur][t];
        if (t >= off) x += sc[cur][t - off];
        sc[cur ^ 1][t] = x; __syncthreads(); cur ^= 1;
    }
    int excl = sc[cur][t] - s;
    int run = partial[blockIdx.x] + excl;
#pragma unroll
    for (int u = 0; u < 4; ++u) {
        int i = base + u;
        if (i < N_NODES) { row_off[i] = run; cursor[i] = run; run += v[u]; }
    }
}

__global__ __launch_bounds__(256) void scatter_kernel(const int* __restrict__ edges,
                                                      const float* __restrict__ sArr,
                                                      int* __restrict__ cursor,
                                                      uint4* __restrict__ csr) {
    int e = blockIdx.x * 256 + threadIdx.x;
    if (e >= N_EDGES) return;
    int s = edges[e], d = edges[N_EDGES + e];
    float4 ss = *(const float4*)(sArr + (size_t)s * 8);
    float4 sd = *(const float4*)(sArr + (size_t)d * 8 + 4);
    unsigned w0 = f2hbits(edge_e(ss.x + sd.x));
    unsigned w1 = f2hbits(edge_e(ss.y + sd.y));
    unsigned w2 = f2hbits(edge_e(ss.z + sd.z));
    unsigned w3 = f2hbits(edge_e(ss.w + sd.w));
    uint4 rec;
    rec.x = (unsigned)s;
    rec.y = w0 | (w1 << 16);
    rec.z = w2 | (w3 << 16);
    rec.w = 0;
    int pos = atomicAdd(&cursor[d], 1);
    csr[pos] = rec;
}

// ---------------------------------------------------------------------------
__device__ __forceinline__ float pickw(const uint4& r, int kh) {
    unsigned wp = (kh & 2) ? r.z : r.y;
    return hbits2f((unsigned short)((kh & 1) ? (wp >> 16) : (wp & 0xffff)));
}
// packed fp16 accumulate: 4x v_pk_fma_f16 per 16B gather
__device__ __forceinline__ void hacc(__half2& a0, __half2& a1, __half2& a2,
                                     __half2& a3, uint4 g, __half2 w) {
    a0 = __hfma2(*(__half2*)&g.x, w, a0);
    a1 = __hfma2(*(__half2*)&g.y, w, a1);
    a2 = __hfma2(*(__half2*)&g.z, w, a2);
    a3 = __hfma2(*(__half2*)&g.w, w, a3);
}

// msg_csr: one wave per dst. es=lane>>5 (edge slot), kh=(lane&31)>>3 (head),
// cg=lane&7 (col octet). 16B gather/lane, pk_fma_f16 accumulate, 8/4/2-edge
// unroll ladder for MLP; final reduce + store in f32.
__global__ __launch_bounds__(256) void msg_csr(const int* __restrict__ row_off,
                                               const int* __restrict__ deg,
                                               const uint4* __restrict__ csr,
                                               const __half* __restrict__ hw,
                                               float* __restrict__ out) {
    int wid  = (blockIdx.x * 256 + threadIdx.x) >> 6;
    int lane = threadIdx.x & 63;
    if (wid >= N_NODES) return;
    const int start = row_off[wid];
    const int dg    = deg[wid];

    // pass 1: denominators (all lanes, strided)
    float4 den = make_float4(0.f, 0.f, 0.f, 0.f);
    for (int i = lane; i < dg; i += 64) {
        uint4 rec = csr[start + i];
        den.x += hbits2f((unsigned short)(rec.y & 0xffff));
        den.y += hbits2f((unsigned short)(rec.y >> 16));
        den.z += hbits2f((unsigned short)(rec.z & 0xffff));
        den.w += hbits2f((unsigned short)(rec.z >> 16));
    }
#pragma unroll
    for (int off = 32; off > 0; off >>= 1) {
        den.x += __shfl_xor(den.x, off);
        den.y += __shfl_xor(den.y, off);
        den.z += __shfl_xor(den.z, off);
        den.w += __shfl_xor(den.w, off);
    }
    const int es = lane >> 5;           // edge slot 0/1
    const int kh = (lane & 31) >> 3;    // head
    const int cg = lane & 7;            // col octet
    float invk = kh == 0 ? den.x : kh == 1 ? den.y : kh == 2 ? den.z : den.w;
    invk = invk > 0.f ? 0.25f / invk : 0.f;

    // pass 2: 16B/lane gathers, packed fp16 accumulate
    const size_t coff = (size_t)((kh << 6) + (cg << 3));   // halfs within row
    const __half2 hz = __half2half2(__float2half(0.f));
    __half2 a0 = hz, a1 = hz, a2 = hz, a3 = hz;
    int i = 0;
    for (; i + 8 <= dg; i += 8) {                 // 4 gathers in flight
        uint4 r0 = csr[start + i     + es];
        uint4 r1 = csr[start + i + 2 + es];
        uint4 r2 = csr[start + i + 4 + es];
        uint4 r3 = csr[start + i + 6 + es];
        uint4 g0 = *(const uint4*)(hw + (((size_t)r0.x) << 8) + coff);
        uint4 g1 = *(const uint4*)(hw + (((size_t)r1.x) << 8) + coff);
        uint4 g2 = *(const uint4*)(hw + (((size_t)r2.x) << 8) + coff);
        uint4 g3 = *(const uint4*)(hw + (((size_t)r3.x) << 8) + coff);
        __half2 w0 = __half2half2(__float2half(pickw(r0, kh) * invk));
        __half2 w1 = __half2half2(__float2half(pickw(r1, kh) * invk));
        __half2 w2 = __half2half2(__float2half(pickw(r2, kh) * invk));
        __half2 w3 = __half2half2(__float2half(pickw(r3, kh) * invk));
        hacc(a0, a1, a2, a3, g0, w0);
        hacc(a0, a1, a2, a3, g1, w1);
        hacc(a0, a1, a2, a3, g2, w2);
        hacc(a0, a1, a2, a3, g3, w3);
    }
    for (; i + 4 <= dg; i += 4) {                 // 2 gathers in flight
        uint4 r0 = csr[start + i     + es];
        uint4 r1 = csr[start + i + 2 + es];
        uint4 g0 = *(const uint4*)(hw + (((size_t)r0.x) << 8) + coff);
        uint4 g1 = *(const uint4*)(hw + (((size_t)r1.x) << 8) + coff);
        __half2 w0 = __half2half2(__float2half(pickw(r0, kh) * invk));
        __half2 w1 = __half2half2(__float2half(pickw(r1, kh) * invk));
        hacc(a0, a1, a2, a3, g0, w0);
        hacc(a0, a1, a2, a3, g1, w1);
    }
    for (; i < dg; i += 2) {                      // tail (clamped)
        int idx = i + es;
        bool valid = idx < dg;
        if (idx >= dg) idx = dg - 1;
        uint4 r = csr[start + idx];
        uint4 g = *(const uint4*)(hw + (((size_t)r.x) << 8) + coff);
        float wf = valid ? pickw(r, kh) * invk : 0.f;
        hacc(a0, a1, a2, a3, g, __half2half2(__float2half(wf)));
    }

    // convert to f32, reduce heads (xor 8,16) + edge slots (xor 32)
    float2 f0 = __half22float2(a0), f1 = __half22float2(a1);
    float2 f2 = __half22float2(a2), f3 = __half22float2(a3);
    float4 alo = make_float4(f0.x, f0.y, f1.x, f1.y);
    float4 ahi = make_float4(f2.x, f2.y, f3.x, f3.y);
#pragma unroll
    for (int off = 8; off < 64; off <<= 1) {
        alo.x += __shfl_xor(alo.x, off); alo.y += __shfl_xor(alo.y, off);
        alo.z += __shfl_xor(alo.z, off); alo.w += __shfl_xor(alo.w, off);
        ahi.x += __shfl_xor(ahi.x, off); ahi.y += __shfl_xor(ahi.y, off);
        ahi.z += __shfl_xor(ahi.z, off); ahi.w += __shfl_xor(ahi.w, off);
    }
    if (lane < 8) {
        float* op = out + (size_t)wid * OUT_DIM + (cg << 3);
        *(float4*)op       = alo;
        *(float4*)(op + 4) = ahi;
    }
}

// ---------------------------------------------------------------------------
extern "C" void kernel_launch(void* const* d_in, const int* in_sizes, int n_in,
                              void* d_out, int out_size, void* d_ws, size_t ws_size,
                              hipStream_t stream) {
    const float* h     = (const float*)d_in[0];
    const int*   edges = (const int*)d_in[1];
    const float* W     = (const float*)d_in[2];
    const float* a     = (const float*)d_in[3];
    float* out = (float*)d_out;

    char* ws = (char*)d_ws;
    __half* hw      = (__half*)(ws);                    // 51,200,000 B  [N][256] f16
    float*  sArr    = (float*) (ws + 51200000);         //  3,200,000 B
    float*  Wa      = (float*) (ws + 54400000);         //      4,096 B
    short*  WcatT   = (short*) (ws + 54404096);         //     65,536 B
    int*    deg     = (int*)   (ws + 54469632);         //    400,000 B
    int*    row_off = (int*)   (ws + 54869632);         //    400,000 B
    int*    cursor  = (int*)   (ws + 55269632);         //    400,000 B
    int*    partial = (int*)   (ws + 55669632);         //      4,096 B
    uint4*  csr     = (uint4*) (ws + 55673728);         // 25,600,000 B

    const int NB_SCAN = (N_NODES + 1023) / 1024;        // 98

    hipMemsetAsync(deg, 0, (size_t)N_NODES * sizeof(int), stream);

    prep_kernel<<<132, 256, 0, stream>>>(W, a, WcatT, Wa);
    s_kernel<<<(N_NODES + 255) / 256, 256, 0, stream>>>(h, Wa, sArr);
    gemm_mfma<<<(N_NODES + 63) / 64, 256, 0, stream>>>(h, WcatT, hw);

    deg_hist<<<(N_EDGES + 255) / 256, 256, 0, stream>>>(edges, deg);
    deg_blocksum<<<NB_SCAN, 256, 0, stream>>>(deg, partial);
    scan_partials<<<1, 128, 0, stream>>>(partial, NB_SCAN);
    deg_scan_write<<<NB_SCAN, 256, 0, stream>>>(deg, partial, row_off, cursor);
    scatter_kernel<<<(N_EDGES + 255) / 256, 256, 0, stream>>>(edges, sArr, cursor, csr);

    msg_csr<<<(N_NODES + 3) / 4, 256, 0, stream>>>(row_off, deg, csr, hw, out);
}

// Round 8
// 318.102 us; speedup vs baseline: 1.1886x; 1.0170x over previous
//
#include <hip/hip_runtime.h>
#include <hip/hip_fp16.h>

#define N_NODES 100000
#define N_EDGES 1600000
#define IN_DIM  128
#define OUT_DIM 64
#define HEADS   4
#define SLOPE   0.2f
#define CLIP_LO 0.005f
#define CLIP_HI 10.0f
#define HIST_BLOCKS 6250   // ceil(N_EDGES/256)

typedef short bf16x8 __attribute__((ext_vector_type(8)));
typedef float f32x4  __attribute__((ext_vector_type(4)));

__device__ __forceinline__ short f2bf(float x) {
    union { float f; unsigned u; } v; v.f = x;
    unsigned r = (v.u + 0x7FFF + ((v.u >> 16) & 1)) >> 16;   // RNE
    return (short)r;
}
__device__ __forceinline__ unsigned short f2hbits(float x) {
    union { __half h; unsigned short u; } c; c.h = __float2half(x); return c.u;
}
__device__ __forceinline__ float hbits2f(unsigned short b) {
    union { __half h; unsigned short u; } c; c.u = b; return __half2float(c.h);
}

// ---------------------------------------------------------------------------
// prep_hist: blocks [0,HIST_BLOCKS) do the dst-degree histogram;
// blocks [HIST_BLOCKS, +132) build WcatT (bf16 B-matrix) and Wa (score GEMV).
// ---------------------------------------------------------------------------
__global__ __launch_bounds__(256) void prep_hist(const float* __restrict__ W,
                                                 const float* __restrict__ a,
                                                 const int* __restrict__ edges,
                                                 short* __restrict__ WcatT,
                                                 float* __restrict__ Wa,
                                                 int* __restrict__ deg) {
    int b = blockIdx.x;
    if (b < HIST_BLOCKS) {
        int e = b * 256 + threadIdx.x;
        if (e < N_EDGES) atomicAdd(&deg[edges[N_EDGES + e]], 1);
        return;
    }
    int idx = (b - HIST_BLOCKS) * 256 + threadIdx.x;
    if (idx < 256 * 128) {
        int n = idx >> 7, i = idx & 127;
        int k = n >> 6, j = n & 63;
        WcatT[idx] = f2bf(W[((size_t)k * IN_DIM + i) * OUT_DIM + j]);
    } else if (idx < 256 * 128 + 1024) {
        int o = idx - 256 * 128;
        int k = o >> 8, half = (o >> 7) & 1, i = o & 127;
        const float* wrow = W + ((size_t)k * IN_DIM + i) * OUT_DIM;
        const float* av   = a + k * 2 * OUT_DIM + half * OUT_DIM;
        float acc = 0.f;
#pragma unroll 8
        for (int j = 0; j < OUT_DIM; ++j) acc += wrow[j] * av[j];
        Wa[o] = acc;
    }
}

// ---------------------------------------------------------------------------
// s_kernel: exact f32 scores via h @ Wa
// ---------------------------------------------------------------------------
__global__ __launch_bounds__(256) void s_kernel(const float* __restrict__ h,
                                                const float* __restrict__ Wa,
                                                float* __restrict__ sArr) {
    __shared__ __align__(16) float wa_s[HEADS * 2 * IN_DIM];
    for (int t = threadIdx.x; t < HEADS * 2 * IN_DIM; t += 256) wa_s[t] = Wa[t];
    __syncthreads();
    int n = blockIdx.x * 256 + threadIdx.x;
    if (n >= N_NODES) return;
    const float4* hv = (const float4*)(h + (size_t)n * IN_DIM);
    const float4* wv = (const float4*)wa_s;
    float acc[8] = {0.f,0.f,0.f,0.f,0.f,0.f,0.f,0.f};
    for (int i4 = 0; i4 < IN_DIM / 4; ++i4) {
        float4 hx = hv[i4];
#pragma unroll
        for (int k2 = 0; k2 < 8; ++k2) {
            float4 w = wv[k2 * (IN_DIM / 4) + i4];
            acc[k2] += hx.x * w.x + hx.y * w.y + hx.z * w.z + hx.w * w.w;
        }
    }
    float* o = sArr + (size_t)n * 8;
#pragma unroll
    for (int k = 0; k < 4; ++k) { o[k] = acc[2 * k]; o[4 + k] = acc[2 * k + 1]; }
}

// ---------------------------------------------------------------------------
// gemm_mfma: hw[n][k*64+j] (fp16, node-major [N][256]) = h @ Wcat via bf16 MFMA
// Epilogue staged through LDS for coalesced dwordx4 stores. (R4-proven)
// ---------------------------------------------------------------------------
__global__ __launch_bounds__(256) void gemm_mfma(const float* __restrict__ h,
                                                 const short* __restrict__ WcatT,
                                                 __half* __restrict__ hw) {
    __shared__ __align__(16) short As[64][136];            // 17.4KB
    __shared__ __align__(16) unsigned short Cs[64][264];   // 33.8KB
    const int row0 = blockIdx.x * 64;
    const int tid  = threadIdx.x;

#pragma unroll
    for (int u = 0; u < 4; ++u) {
        int e = (tid + u * 256) * 8;
        int r = e >> 7, c = e & 127;
        int grow = row0 + r; if (grow >= N_NODES) grow = N_NODES - 1;
        const float* hp = h + (size_t)grow * IN_DIM + c;
        float4 v0 = *(const float4*)hp;
        float4 v1 = *(const float4*)(hp + 4);
        bf16x8 b;
        b[0]=f2bf(v0.x); b[1]=f2bf(v0.y); b[2]=f2bf(v0.z); b[3]=f2bf(v0.w);
        b[4]=f2bf(v1.x); b[5]=f2bf(v1.y); b[6]=f2bf(v1.z); b[7]=f2bf(v1.w);
        *(bf16x8*)&As[r][c] = b;
    }
    __syncthreads();

    const int wv = tid >> 6, lane = tid & 63;
    const int lrow = lane & 15;
    const int lk   = (lane >> 4) * 8;

    bf16x8 bfr[4][4];
#pragma unroll
    for (int nt = 0; nt < 4; ++nt)
#pragma unroll
        for (int ks = 0; ks < 4; ++ks)
            bfr[nt][ks] = *(const bf16x8*)(WcatT + (size_t)(wv * 64 + nt * 16 + lrow) * 128 + ks * 32 + lk);

    f32x4 acc[4][4] = {};
#pragma unroll
    for (int ks = 0; ks < 4; ++ks) {
        bf16x8 afr[4];
#pragma unroll
        for (int mt = 0; mt < 4; ++mt)
            afr[mt] = *(const bf16x8*)&As[mt * 16 + lrow][ks * 32 + lk];
#pragma unroll
        for (int mt = 0; mt < 4; ++mt)
#pragma unroll
            for (int nt = 0; nt < 4; ++nt)
                acc[mt][nt] = __builtin_amdgcn_mfma_f32_16x16x32_bf16(afr[mt], bfr[nt][ks], acc[mt][nt], 0, 0, 0);
    }

    const int rgrp = lane >> 4;
#pragma unroll
    for (int mt = 0; mt < 4; ++mt)
#pragma unroll
        for (int reg = 0; reg < 4; ++reg) {
            int r = mt * 16 + rgrp * 4 + reg;
#pragma unroll
            for (int nt = 0; nt < 4; ++nt)
                Cs[r][wv * 64 + nt * 16 + lrow] = f2hbits(acc[mt][nt][reg]);
        }
    __syncthreads();

    {
        const int r  = tid >> 2;
        const int c0 = (tid & 3) * 64;
        int g = row0 + r;
        if (g < N_NODES) {
            const uint4* src = (const uint4*)&Cs[r][c0];
            uint4* dst = (uint4*)(hw + (size_t)g * 256 + c0);
#pragma unroll
            for (int u = 0; u < 8; ++u) dst[u] = src[u];
        }
    }
}

// ---------------------------------------------------------------------------
__device__ __forceinline__ float edge_e(float x) {
    x = x > 0.f ? x : SLOPE * x;
    float ev = __expf(x);
    return fminf(fmaxf(ev, CLIP_LO), CLIP_HI);
}

__global__ __launch_bounds__(256) void deg_blocksum(const int* __restrict__ deg,
                                                    int* __restrict__ partial) {
    __shared__ int red[256];
    int base = blockIdx.x * 1024 + threadIdx.x * 4;
    int s = 0;
#pragma unroll
    for (int u = 0; u < 4; ++u) { int i = base + u; if (i < N_NODES) s += deg[i]; }
    red[threadIdx.x] = s; __syncthreads();
    for (int off = 128; off > 0; off >>= 1) {
        if (threadIdx.x < off) red[threadIdx.x] += red[threadIdx.x + off];
        __syncthreads();
    }
    if (threadIdx.x == 0) partial[blockIdx.x] = red[0];
}

__global__ __launch_bounds__(128) void scan_partials(int* __restrict__ partial, int nb) {
    __shared__ int sm[128];
    int t = threadIdx.x;
    sm[t] = (t < nb) ? partial[t] : 0;
    __syncthreads();
    if (t == 0) {
        int run = 0;
        for (int i = 0; i < nb; ++i) { int v = sm[i]; sm[i] = run; run += v; }
    }
    __syncthreads();
    if (t < nb) partial[t] = sm[t];
}

__global__ __launch_bounds__(256) void deg_scan_write(const int* __restrict__ deg,
                                                      const int* __restrict__ partial,
                                                      int* __restrict__ row_off,
                                                      int* __restrict__ cursor) {
    __shared__ int sc[2][256];
    int t = threadIdx.x;
    int base = blockIdx.x * 1024 + t * 4;
    int v[4]; int s = 0;
#pragma unroll
    for (int u = 0; u < 4; ++u) { int i = base + u; v[u] = (i < N_NODES) ? deg[i] : 0; s += v[u]; }
    sc[0][t] = s; __syncthreads();
    int cur = 0;
    for (int off = 1; off < 256; off <<= 1) {
        int x = sc[cur][t];
        if (t >= off) x += sc[cur][t - off];
        sc[cur ^ 1][t] = x; __syncthreads(); cur ^= 1;
    }
    int excl = sc[cur][t] - s;
    int run = partial[blockIdx.x] + excl;
#pragma unroll
    for (int u = 0; u < 4; ++u) {
        int i = base + u;
        if (i < N_NODES) { row_off[i] = run; cursor[i] = run; run += v[u]; }
    }
}

__global__ __launch_bounds__(256) void scatter_kernel(const int* __restrict__ edges,
                                                      const float* __restrict__ sArr,
                                                      int* __restrict__ cursor,
                                                      uint4* __restrict__ csr) {
    int e = blockIdx.x * 256 + threadIdx.x;
    if (e >= N_EDGES) return;
    int s = edges[e], d = edges[N_EDGES + e];
    float4 ss = *(const float4*)(sArr + (size_t)s * 8);
    float4 sd = *(const float4*)(sArr + (size_t)d * 8 + 4);
    unsigned w0 = f2hbits(edge_e(ss.x + sd.x));
    unsigned w1 = f2hbits(edge_e(ss.y + sd.y));
    unsigned w2 = f2hbits(edge_e(ss.z + sd.z));
    unsigned w3 = f2hbits(edge_e(ss.w + sd.w));
    uint4 rec;
    rec.x = (unsigned)s;
    rec.y = w0 | (w1 << 16);
    rec.z = w2 | (w3 << 16);
    rec.w = 0;
    int pos = atomicAdd(&cursor[d], 1);
    csr[pos] = rec;
}

// ---------------------------------------------------------------------------
__device__ __forceinline__ float pickw(const uint4& r, int kh) {
    unsigned wp = (kh & 2) ? r.z : r.y;
    return hbits2f((unsigned short)((kh & 1) ? (wp >> 16) : (wp & 0xffff)));
}
__device__ __forceinline__ void fmacc8(float4& lo, float4& hi, uint4 g, float w) {
    __half2 h0 = *(__half2*)&g.x, h1 = *(__half2*)&g.y;
    __half2 h2 = *(__half2*)&g.z, h3 = *(__half2*)&g.w;
    float2 f0 = __half22float2(h0), f1 = __half22float2(h1);
    float2 f2 = __half22float2(h2), f3 = __half22float2(h3);
    lo.x += w * f0.x; lo.y += w * f0.y; lo.z += w * f1.x; lo.w += w * f1.y;
    hi.x += w * f2.x; hi.y += w * f2.y; hi.z += w * f3.x; hi.w += w * f3.y;
}

// msg_csr SINGLE-PASS: accumulate unnormalized e*hw in f32 AND the per-head
// denominator from the same decoded records; normalize at the end.
// es=lane>>5 (edge slot), kh=(lane&31)>>3 (head), cg=lane&7 (col octet).
__global__ __launch_bounds__(256) void msg_csr(const int* __restrict__ row_off,
                                               const int* __restrict__ deg,
                                               const uint4* __restrict__ csr,
                                               const __half* __restrict__ hw,
                                               float* __restrict__ out) {
    int wid  = (blockIdx.x * 256 + threadIdx.x) >> 6;
    int lane = threadIdx.x & 63;
    if (wid >= N_NODES) return;
    const int start = row_off[wid];
    const int dg    = deg[wid];

    const int es = lane >> 5;           // edge slot 0/1
    const int kh = (lane & 31) >> 3;    // head
    const int cg = lane & 7;            // col octet
    const size_t coff = (size_t)((kh << 6) + (cg << 3));   // halfs within row

    float4 alo = make_float4(0.f,0.f,0.f,0.f), ahi = make_float4(0.f,0.f,0.f,0.f);
    float den = 0.f;
    int i = 0;
    for (; i + 8 <= dg; i += 8) {                 // 4 gathers in flight
        uint4 r0 = csr[start + i     + es];
        uint4 r1 = csr[start + i + 2 + es];
        uint4 r2 = csr[start + i + 4 + es];
        uint4 r3 = csr[start + i + 6 + es];
        uint4 g0 = *(const uint4*)(hw + (((size_t)r0.x) << 8) + coff);
        uint4 g1 = *(const uint4*)(hw + (((size_t)r1.x) << 8) + coff);
        uint4 g2 = *(const uint4*)(hw + (((size_t)r2.x) << 8) + coff);
        uint4 g3 = *(const uint4*)(hw + (((size_t)r3.x) << 8) + coff);
        float w0 = pickw(r0, kh);
        float w1 = pickw(r1, kh);
        float w2 = pickw(r2, kh);
        float w3 = pickw(r3, kh);
        den += (w0 + w1) + (w2 + w3);
        fmacc8(alo, ahi, g0, w0);
        fmacc8(alo, ahi, g1, w1);
        fmacc8(alo, ahi, g2, w2);
        fmacc8(alo, ahi, g3, w3);
    }
    for (; i + 4 <= dg; i += 4) {                 // 2 gathers in flight
        uint4 r0 = csr[start + i     + es];
        uint4 r1 = csr[start + i + 2 + es];
        uint4 g0 = *(const uint4*)(hw + (((size_t)r0.x) << 8) + coff);
        uint4 g1 = *(const uint4*)(hw + (((size_t)r1.x) << 8) + coff);
        float w0 = pickw(r0, kh);
        float w1 = pickw(r1, kh);
        den += w0 + w1;
        fmacc8(alo, ahi, g0, w0);
        fmacc8(alo, ahi, g1, w1);
    }
    for (; i < dg; i += 2) {                      // tail (clamped)
        int idx = i + es;
        bool valid = idx < dg;
        if (idx >= dg) idx = dg - 1;
        uint4 r = csr[start + idx];
        uint4 g = *(const uint4*)(hw + (((size_t)r.x) << 8) + coff);
        float w = valid ? pickw(r, kh) : 0.f;
        den += w;
        fmacc8(alo, ahi, g, w);
    }

    // denominator: slot0+slot1 (cg-duplicates are identical, no extra reduce)
    den += __shfl_xor(den, 32);
    float invk = den > 0.f ? 0.25f / den : 0.f;
    alo.x *= invk; alo.y *= invk; alo.z *= invk; alo.w *= invk;
    ahi.x *= invk; ahi.y *= invk; ahi.z *= invk; ahi.w *= invk;

    // reduce heads (xor 8,16) + edge slots (xor 32)
#pragma unroll
    for (int off = 8; off < 64; off <<= 1) {
        alo.x += __shfl_xor(alo.x, off); alo.y += __shfl_xor(alo.y, off);
        alo.z += __shfl_xor(alo.z, off); alo.w += __shfl_xor(alo.w, off);
        ahi.x += __shfl_xor(ahi.x, off); ahi.y += __shfl_xor(ahi.y, off);
        ahi.z += __shfl_xor(ahi.z, off); ahi.w += __shfl_xor(ahi.w, off);
    }
    if (lane < 8) {
        float* op = out + (size_t)wid * OUT_DIM + (cg << 3);
        *(float4*)op       = alo;
        *(float4*)(op + 4) = ahi;
    }
}

// ---------------------------------------------------------------------------
extern "C" void kernel_launch(void* const* d_in, const int* in_sizes, int n_in,
                              void* d_out, int out_size, void* d_ws, size_t ws_size,
                              hipStream_t stream) {
    const float* h     = (const float*)d_in[0];
    const int*   edges = (const int*)d_in[1];
    const float* W     = (const float*)d_in[2];
    const float* a     = (const float*)d_in[3];
    float* out = (float*)d_out;

    char* ws = (char*)d_ws;
    __half* hw      = (__half*)(ws);                    // 51,200,000 B  [N][256] f16
    float*  sArr    = (float*) (ws + 51200000);         //  3,200,000 B
    float*  Wa      = (float*) (ws + 54400000);         //      4,096 B
    short*  WcatT   = (short*) (ws + 54404096);         //     65,536 B
    int*    deg     = (int*)   (ws + 54469632);         //    400,000 B
    int*    row_off = (int*)   (ws + 54869632);         //    400,000 B
    int*    cursor  = (int*)   (ws + 55269632);         //    400,000 B
    int*    partial = (int*)   (ws + 55669632);         //      4,096 B
    uint4*  csr     = (uint4*) (ws + 55673728);         // 25,600,000 B

    const int NB_SCAN = (N_NODES + 1023) / 1024;        // 98

    hipMemsetAsync(deg, 0, (size_t)N_NODES * sizeof(int), stream);

    prep_hist<<<HIST_BLOCKS + 132, 256, 0, stream>>>(W, a, edges, WcatT, Wa, deg);
    s_kernel<<<(N_NODES + 255) / 256, 256, 0, stream>>>(h, Wa, sArr);
    gemm_mfma<<<(N_NODES + 63) / 64, 256, 0, stream>>>(h, WcatT, hw);

    deg_blocksum<<<NB_SCAN, 256, 0, stream>>>(deg, partial);
    scan_partials<<<1, 128, 0, stream>>>(partial, NB_SCAN);
    deg_scan_write<<<NB_SCAN, 256, 0, stream>>>(deg, partial, row_off, cursor);
    scatter_kernel<<<(N_EDGES + 255) / 256, 256, 0, stream>>>(edges, sArr, cursor, csr);

    msg_csr<<<(N_NODES + 3) / 4, 256, 0, stream>>>(row_off, deg, csr, hw, out);
}